// Round 9
// baseline (480.561 us; speedup 1.0000x reference)
//
#include <hip/hip_runtime.h>

constexpr int IN_F  = 128;
constexpr int OUT_F = 64;
constexpr int NB_BLOCKS = 256;   // edge-chunk blocks; == colscan block size
constexpr int BIN_SHIFT = 6;     // 64 nodes per bin
constexpr int MAX_BINS  = 1024;  // LDS arrays sized for this; N <= 65536

// ---------------- GEMM: h = feats @ weight (unchanged from R7) ----------------
__global__ void gemm_kernel(const float* __restrict__ feats,
                            const float* __restrict__ weight,
                            float* __restrict__ h, int n_nodes) {
    __shared__ float w[IN_F][OUT_F];   // 32 KB
    __shared__ float f[32][IN_F];      // 16 KB feats tile
    for (int i = threadIdx.x; i < IN_F * OUT_F; i += blockDim.x)
        w[i >> 6][i & 63] = weight[i];

    const int lane = threadIdx.x & 63;
    const int wid  = threadIdx.x >> 6;

    const int tile = blockIdx.x * 32;
    const int nn = min(32, n_nodes - tile);

    for (int i = threadIdx.x; i < nn * (IN_F / 4); i += blockDim.x) {
        const int r = i >> 5, c4 = i & 31;
        reinterpret_cast<float4*>(f[r])[c4] =
            reinterpret_cast<const float4*>(feats + (size_t)(tile + r) * IN_F)[c4];
    }
    __syncthreads();

    const int row0 = wid * 8;
    float acc[8] = {0.f, 0.f, 0.f, 0.f, 0.f, 0.f, 0.f, 0.f};

    #pragma unroll 8
    for (int k4 = 0; k4 < IN_F / 4; ++k4) {
        float4 fv[8];
        #pragma unroll
        for (int t = 0; t < 8; ++t)
            fv[t] = reinterpret_cast<const float4*>(f[row0 + t])[k4];
        #pragma unroll
        for (int c = 0; c < 4; ++c) {
            const float wv = w[k4 * 4 + c][lane];
            #pragma unroll
            for (int t = 0; t < 8; ++t)
                acc[t] += (&fv[t].x)[c] * wv;
        }
    }

    #pragma unroll
    for (int t = 0; t < 8; ++t) {
        const int n = tile + row0 + t;
        if (n < n_nodes) h[(size_t)n * OUT_F + lane] = acc[t];
    }
}

// ---------------- B1: per-chunk LDS histogram over bins ----------------
__global__ void hist_kernel(const int* __restrict__ dst, int* __restrict__ histmat,
                            int E, int nbins) {
    __shared__ int hl[MAX_BINS];
    const int k = blockIdx.x;
    const int chunk = (E + NB_BLOCKS - 1) / NB_BLOCKS;
    const int beg = k * chunk, end = min(E, beg + chunk);
    for (int i = threadIdx.x; i < nbins; i += blockDim.x) hl[i] = 0;
    __syncthreads();
    for (int e = beg + threadIdx.x; e < end; e += blockDim.x)
        atomicAdd(&hl[dst[e] >> BIN_SHIFT], 1);
    __syncthreads();
    for (int i = threadIdx.x; i < nbins; i += blockDim.x)
        histmat[k * nbins + i] = hl[i];
}

// ---------------- S1: per-bin exclusive scan over the 256 chunks ----------------
// grid = nbins blocks, block = NB_BLOCKS threads. histmat[k][b] -> exclusive
// prefix over k (in place); tot[b] = column total.
__global__ void colscan_kernel(int* __restrict__ histmat, int* __restrict__ tot, int nbins) {
    __shared__ int s[NB_BLOCKS];
    const int b = blockIdx.x;
    const int t = threadIdx.x;
    const int v = histmat[t * nbins + b];
    s[t] = v;
    __syncthreads();
    for (int off = 1; off < NB_BLOCKS; off <<= 1) {
        const int u = (t >= off) ? s[t - off] : 0;
        __syncthreads();
        s[t] += u;
        __syncthreads();
    }
    histmat[t * nbins + b] = s[t] - v;  // exclusive over blocks
    if (t == NB_BLOCKS - 1) tot[b] = s[t];
}

// ---------------- S2: exclusive scan of bin totals ----------------
__global__ void binscan_kernel(const int* __restrict__ tot, int* __restrict__ binbase,
                               int nbins, int E) {
    __shared__ int s[MAX_BINS];
    const int t = threadIdx.x;
    const int v = (t < nbins) ? tot[t] : 0;
    s[t] = v;
    __syncthreads();
    for (int off = 1; off < MAX_BINS; off <<= 1) {
        const int u = (t >= off) ? s[t - off] : 0;
        __syncthreads();
        s[t] += u;
        __syncthreads();
    }
    if (t < nbins) binbase[t] = s[t] - v;
    if (t == 0) binbase[nbins] = E;
}

// ---------------- B2: deterministic scatter (LDS cursors only) ----------------
__global__ void scatter_kernel(const int* __restrict__ src, const int* __restrict__ dst,
                               const int* __restrict__ colscan, const int* __restrict__ binbase,
                               unsigned int* __restrict__ bucket, int E, int nbins) {
    __shared__ int cur[MAX_BINS];
    const int k = blockIdx.x;
    for (int i = threadIdx.x; i < nbins; i += blockDim.x)
        cur[i] = binbase[i] + colscan[k * nbins + i];
    __syncthreads();
    const int chunk = (E + NB_BLOCKS - 1) / NB_BLOCKS;
    const int beg = k * chunk, end = min(E, beg + chunk);
    for (int e = beg + threadIdx.x; e < end; e += blockDim.x) {
        const int d = dst[e];
        const int pos = atomicAdd(&cur[d >> BIN_SHIFT], 1);
        bucket[pos] = ((unsigned)(d & 63) << 16) | (unsigned)src[e];
    }
}

// ---------------- C: per-bin LDS-tile aggregation + bias + ReLU ----------------
// grid = nbins blocks, 256 threads (4 waves). Edges for bin b are contiguous
// in bucket[binbase[b]..binbase[b+1]). Lane = output column.
__global__ void binagg_kernel(const float* __restrict__ h, const unsigned int* __restrict__ bucket,
                              const int* __restrict__ binbase, const float* __restrict__ bias,
                              float* __restrict__ out, int N) {
    __shared__ float tile[64][OUT_F];  // 16 KB
    const int b    = blockIdx.x;
    const int t    = threadIdx.x;
    const int lane = t & 63;
    const int w    = t >> 6;  // wave 0..3

    float* tf = &tile[0][0];
    for (int i = t; i < 64 * OUT_F; i += 256) tf[i] = 0.f;
    __syncthreads();

    const int base = binbase[b], end = binbase[b + 1];
    const int cnt  = end - base;
    const int kblk = (cnt / 32) * 32;

    // blocked: each wave takes 8 consecutive edges per 32-edge super-group
    for (int i0 = base + w * 8; i0 < base + kblk; i0 += 32) {
        unsigned wd[8];
        float    v[8];
        #pragma unroll
        for (int j = 0; j < 8; ++j) wd[j] = bucket[i0 + j];
        #pragma unroll
        for (int j = 0; j < 8; ++j) v[j] = h[(size_t)(wd[j] & 0xffffu) * OUT_F + lane];
        #pragma unroll
        for (int j = 0; j < 8; ++j) atomicAdd(&tile[wd[j] >> 16][lane], v[j]);
    }
    // tail
    for (int i = base + kblk + w; i < end; i += 4) {
        const unsigned wd = bucket[i];
        atomicAdd(&tile[wd >> 16][lane], h[(size_t)(wd & 0xffffu) * OUT_F + lane]);
    }
    __syncthreads();

    // write out: thread t stores 4 float4s at float4-index t + 256*j (coalesced)
    const float4 bv = reinterpret_cast<const float4*>(bias)[t & 15];
    const float4* t4 = reinterpret_cast<const float4*>(tf);
    #pragma unroll
    for (int j = 0; j < 4; ++j) {
        const int p   = t + 256 * j;   // 0..1023 float4s
        const int row = p >> 4;        // 16 float4 per row
        const int g   = b * 64 + row;
        if (g < N) {
            float4 v = t4[p];
            v.x = fmaxf(v.x + bv.x, 0.f);
            v.y = fmaxf(v.y + bv.y, 0.f);
            v.z = fmaxf(v.z + bv.z, 0.f);
            v.w = fmaxf(v.w + bv.w, 0.f);
            reinterpret_cast<float4*>(out)[(size_t)g * (OUT_F / 4) + (p & 15)] = v;
        }
    }
}

extern "C" void kernel_launch(void* const* d_in, const int* in_sizes, int n_in,
                              void* d_out, int out_size, void* d_ws, size_t ws_size,
                              hipStream_t stream) {
    const float* feats  = (const float*)d_in[0];
    const float* weight = (const float*)d_in[1];
    const float* bias   = (const float*)d_in[2];
    const int*   src    = (const int*)d_in[3];
    const int*   dst    = (const int*)d_in[4];
    float* out = (float*)d_out;

    const int N = in_sizes[0] / IN_F;
    const int E = in_sizes[3];
    const int nbins = (N + 63) >> BIN_SHIFT;  // 782 for N=50000 (<= MAX_BINS)

    // workspace layout (~16.9 MB)
    float*    h       = (float*)d_ws;                       // N*64 f32
    unsigned* bucket  = (unsigned*)(h + (size_t)N * OUT_F); // E words
    int*      histmat = (int*)(bucket + E);                 // NB_BLOCKS * nbins
    int*      tot     = histmat + NB_BLOCKS * nbins;        // nbins
    int*      binbase = tot + nbins;                        // nbins + 1

    gemm_kernel<<<(N + 31) / 32, 256, 0, stream>>>(feats, weight, h, N);
    hist_kernel<<<NB_BLOCKS, 256, 0, stream>>>(dst, histmat, E, nbins);
    colscan_kernel<<<nbins, NB_BLOCKS, 0, stream>>>(histmat, tot, nbins);
    binscan_kernel<<<1, MAX_BINS, 0, stream>>>(tot, binbase, nbins, E);
    scatter_kernel<<<NB_BLOCKS, 256, 0, stream>>>(src, dst, histmat, binbase, bucket, E, nbins);
    binagg_kernel<<<nbins, 256, 0, stream>>>(h, bucket, binbase, bias, out, N);
}

// Round 11
// 184.308 us; speedup vs baseline: 2.6074x; 2.6074x over previous
//
#include <hip/hip_runtime.h>

constexpr int IN_F  = 128;
constexpr int OUT_F = 64;
constexpr int NB_BLOCKS = 256;   // edge-chunk blocks; == colscan block size
constexpr int BIN_SHIFT = 6;     // 64 nodes per bin
constexpr int MAX_BINS  = 1024;  // N <= 65536
constexpr int BIN_CAP   = 8192;  // binsort LDS capacity (words); mean bin ~1023, 8x margin

// ---------------- GEMM: h = feats @ weight ----------------
__global__ void gemm_kernel(const float* __restrict__ feats,
                            const float* __restrict__ weight,
                            float* __restrict__ h, int n_nodes) {
    __shared__ float w[IN_F][OUT_F];   // 32 KB
    __shared__ float f[32][IN_F];      // 16 KB feats tile
    for (int i = threadIdx.x; i < IN_F * OUT_F; i += blockDim.x)
        w[i >> 6][i & 63] = weight[i];

    const int lane = threadIdx.x & 63;
    const int wid  = threadIdx.x >> 6;

    const int tile = blockIdx.x * 32;
    const int nn = min(32, n_nodes - tile);

    for (int i = threadIdx.x; i < nn * (IN_F / 4); i += blockDim.x) {
        const int r = i >> 5, c4 = i & 31;
        reinterpret_cast<float4*>(f[r])[c4] =
            reinterpret_cast<const float4*>(feats + (size_t)(tile + r) * IN_F)[c4];
    }
    __syncthreads();

    const int row0 = wid * 8;
    float acc[8] = {0.f, 0.f, 0.f, 0.f, 0.f, 0.f, 0.f, 0.f};

    #pragma unroll 8
    for (int k4 = 0; k4 < IN_F / 4; ++k4) {
        float4 fv[8];
        #pragma unroll
        for (int t = 0; t < 8; ++t)
            fv[t] = reinterpret_cast<const float4*>(f[row0 + t])[k4];
        #pragma unroll
        for (int c = 0; c < 4; ++c) {
            const float wv = w[k4 * 4 + c][lane];
            #pragma unroll
            for (int t = 0; t < 8; ++t)
                acc[t] += (&fv[t].x)[c] * wv;
        }
    }

    #pragma unroll
    for (int t = 0; t < 8; ++t) {
        const int n = tile + row0 + t;
        if (n < n_nodes) h[(size_t)n * OUT_F + lane] = acc[t];
    }
}

// ---------------- B1: per-chunk LDS histogram over bins ----------------
__global__ void hist_kernel(const int* __restrict__ dst, int* __restrict__ histmat,
                            int E, int nbins) {
    __shared__ int hl[MAX_BINS];
    const int k = blockIdx.x;
    const int chunk = (E + NB_BLOCKS - 1) / NB_BLOCKS;
    const int beg = k * chunk, end = min(E, beg + chunk);
    for (int i = threadIdx.x; i < nbins; i += blockDim.x) hl[i] = 0;
    __syncthreads();
    for (int e = beg + threadIdx.x; e < end; e += blockDim.x)
        atomicAdd(&hl[dst[e] >> BIN_SHIFT], 1);
    __syncthreads();
    for (int i = threadIdx.x; i < nbins; i += blockDim.x)
        histmat[k * nbins + i] = hl[i];
}

// ---------------- S1: per-bin exclusive scan over the 256 chunks ----------------
__global__ void colscan_kernel(int* __restrict__ histmat, int* __restrict__ tot, int nbins) {
    __shared__ int s[NB_BLOCKS];
    const int b = blockIdx.x;
    const int t = threadIdx.x;
    const int v = histmat[t * nbins + b];
    s[t] = v;
    __syncthreads();
    for (int off = 1; off < NB_BLOCKS; off <<= 1) {
        const int u = (t >= off) ? s[t - off] : 0;
        __syncthreads();
        s[t] += u;
        __syncthreads();
    }
    histmat[t * nbins + b] = s[t] - v;  // exclusive over blocks
    if (t == NB_BLOCKS - 1) tot[b] = s[t];
}

// ---------------- S2: exclusive scan of bin totals ----------------
__global__ void binscan_kernel(const int* __restrict__ tot, int* __restrict__ binbase,
                               int nbins, int E) {
    __shared__ int s[MAX_BINS];
    const int t = threadIdx.x;
    const int v = (t < nbins) ? tot[t] : 0;
    s[t] = v;
    __syncthreads();
    for (int off = 1; off < MAX_BINS; off <<= 1) {
        const int u = (t >= off) ? s[t - off] : 0;
        __syncthreads();
        s[t] += u;
        __syncthreads();
    }
    if (t < nbins) binbase[t] = s[t] - v;
    if (t == 0) binbase[nbins] = E;
}

// ---------------- B2: deterministic scatter into bins (LDS cursors only) ----------------
__global__ void scatter_kernel(const int* __restrict__ src, const int* __restrict__ dst,
                               const int* __restrict__ colscan, const int* __restrict__ binbase,
                               unsigned int* __restrict__ bucket, int E, int nbins) {
    __shared__ int cur[MAX_BINS];
    const int k = blockIdx.x;
    for (int i = threadIdx.x; i < nbins; i += blockDim.x)
        cur[i] = binbase[i] + colscan[k * nbins + i];
    __syncthreads();
    const int chunk = (E + NB_BLOCKS - 1) / NB_BLOCKS;
    const int beg = k * chunk, end = min(E, beg + chunk);
    for (int e = beg + threadIdx.x; e < end; e += blockDim.x) {
        const int d = dst[e];
        const int pos = atomicAdd(&cur[d >> BIN_SHIFT], 1);
        bucket[pos] = ((unsigned)(d & 63) << 16) | (unsigned)src[e];  // src < 65536
    }
}

// ---------------- B3: per-bin counting sort (in place) -> per-node CSR offs ----------------
// One block per bin. Loads the bin's packed edges to LDS, histograms the 64
// in-bin node slots, exclusive-scans, scatters back node-sorted, emits offs.
__global__ void binsort_kernel(unsigned int* __restrict__ bucket,
                               const int* __restrict__ binbase,
                               int* __restrict__ offs, int N, int E, int nbins) {
    __shared__ unsigned buf[BIN_CAP];  // 32 KB
    __shared__ int cnt64[64];
    __shared__ int off64[64];
    const int b    = blockIdx.x;
    const int base = binbase[b], end = binbase[b + 1];
    const int cnt  = end - base;  // ~1023 << BIN_CAP for uniform random dst

    for (int i = threadIdx.x; i < cnt; i += 256) buf[i] = bucket[base + i];
    if (threadIdx.x < 64) cnt64[threadIdx.x] = 0;
    __syncthreads();
    for (int i = threadIdx.x; i < cnt; i += 256)
        atomicAdd(&cnt64[buf[i] >> 16], 1);
    __syncthreads();

    // exclusive scan of the 64 counters (Hillis-Steele; all threads hit barriers)
    int v = 0;
    if (threadIdx.x < 64) { v = cnt64[threadIdx.x]; off64[threadIdx.x] = v; }
    __syncthreads();
    for (int off = 1; off < 64; off <<= 1) {
        int u = 0;
        if (threadIdx.x >= off && threadIdx.x < 64) u = off64[threadIdx.x - off];
        __syncthreads();
        if (threadIdx.x < 64) off64[threadIdx.x] += u;
        __syncthreads();
    }
    if (threadIdx.x < 64) {
        const int excl = off64[threadIdx.x] - v;
        const int node = (b << BIN_SHIFT) + threadIdx.x;
        if (node < N) offs[node] = base + excl;
        off64[threadIdx.x] = excl;  // becomes the scatter cursor
    }
    __syncthreads();

    for (int i = threadIdx.x; i < cnt; i += 256) {
        const unsigned wdv = buf[i];
        const int pos = atomicAdd(&off64[wdv >> 16], 1);
        bucket[base + pos] = wdv;
    }
    if (b == nbins - 1 && threadIdx.x == 0) offs[N] = E;
}

// ---------------- C: pull-mode CSR gather + bias + ReLU ----------------
// One wave per node; lane j accumulates column j. 8-deep named unroll for MLP.
__global__ __launch_bounds__(256) void gather_kernel(
        const float* __restrict__ h, const unsigned int* __restrict__ bucket,
        const int* __restrict__ offs, const float* __restrict__ bias,
        float* __restrict__ out, int N) {
    const int lane   = threadIdx.x & 63;
    const int gwave  = (blockIdx.x * blockDim.x + threadIdx.x) >> 6;
    const int nwaves = (gridDim.x * blockDim.x) >> 6;
    const float b = bias[lane];
    for (int n = gwave; n < N; n += nwaves) {
        const int beg = offs[n], end = offs[n + 1];
        float acc = 0.f;
        int i = beg;
        for (; i + 8 <= end; i += 8) {
            const unsigned w0 = bucket[i + 0], w1 = bucket[i + 1];
            const unsigned w2 = bucket[i + 2], w3 = bucket[i + 3];
            const unsigned w4 = bucket[i + 4], w5 = bucket[i + 5];
            const unsigned w6 = bucket[i + 6], w7 = bucket[i + 7];
            const float v0 = h[(size_t)(w0 & 0xffffu) * OUT_F + lane];
            const float v1 = h[(size_t)(w1 & 0xffffu) * OUT_F + lane];
            const float v2 = h[(size_t)(w2 & 0xffffu) * OUT_F + lane];
            const float v3 = h[(size_t)(w3 & 0xffffu) * OUT_F + lane];
            const float v4 = h[(size_t)(w4 & 0xffffu) * OUT_F + lane];
            const float v5 = h[(size_t)(w5 & 0xffffu) * OUT_F + lane];
            const float v6 = h[(size_t)(w6 & 0xffffu) * OUT_F + lane];
            const float v7 = h[(size_t)(w7 & 0xffffu) * OUT_F + lane];
            acc += v0; acc += v1; acc += v2; acc += v3;
            acc += v4; acc += v5; acc += v6; acc += v7;
        }
        for (; i < end; ++i)
            acc += h[(size_t)(bucket[i] & 0xffffu) * OUT_F + lane];
        out[(size_t)n * OUT_F + lane] = fmaxf(acc + b, 0.f);
    }
}

extern "C" void kernel_launch(void* const* d_in, const int* in_sizes, int n_in,
                              void* d_out, int out_size, void* d_ws, size_t ws_size,
                              hipStream_t stream) {
    const float* feats  = (const float*)d_in[0];
    const float* weight = (const float*)d_in[1];
    const float* bias   = (const float*)d_in[2];
    const int*   src    = (const int*)d_in[3];
    const int*   dst    = (const int*)d_in[4];
    float* out = (float*)d_out;

    const int N = in_sizes[0] / IN_F;
    const int E = in_sizes[3];
    const int nbins = (N + 63) >> BIN_SHIFT;  // 782 for N=50000

    // workspace layout (~17.2 MB)
    float*    h       = (float*)d_ws;                       // N*64 f32
    unsigned* bucket  = (unsigned*)(h + (size_t)N * OUT_F); // E words
    int*      histmat = (int*)(bucket + E);                 // NB_BLOCKS * nbins
    int*      tot     = histmat + NB_BLOCKS * nbins;        // nbins
    int*      binbase = tot + nbins;                        // nbins + 1
    int*      offs    = binbase + nbins + 1;                // N + 1

    gemm_kernel<<<(N + 31) / 32, 256, 0, stream>>>(feats, weight, h, N);
    hist_kernel<<<NB_BLOCKS, 256, 0, stream>>>(dst, histmat, E, nbins);
    colscan_kernel<<<nbins, NB_BLOCKS, 0, stream>>>(histmat, tot, nbins);
    binscan_kernel<<<1, MAX_BINS, 0, stream>>>(tot, binbase, nbins, E);
    scatter_kernel<<<NB_BLOCKS, 256, 0, stream>>>(src, dst, histmat, binbase, bucket, E, nbins);
    binsort_kernel<<<nbins, 256, 0, stream>>>(bucket, binbase, offs, N, E, nbins);
    // 2048 x 256 = 8192 waves = full residency; writes every out row (no memset needed)
    gather_kernel<<<2048, 256, 0, stream>>>(h, bucket, offs, bias, out, N);
}

// Round 12
// 152.206 us; speedup vs baseline: 3.1573x; 1.2109x over previous
//
#include <hip/hip_runtime.h>

constexpr int IN_F  = 128;
constexpr int OUT_F = 64;
constexpr int NB_BLOCKS = 256;   // edge-chunk blocks; == colscan block size
constexpr int BIN_SHIFT = 6;     // 64 nodes per bin
constexpr int MAX_BINS  = 1024;  // N <= 65536
constexpr int BIN_CAP   = 8192;  // binsort LDS capacity (words)

using bf16x8 = __attribute__((ext_vector_type(8))) short;  // 8 bf16 in 4 VGPRs
using f32x4  = __attribute__((ext_vector_type(4))) float;

__device__ inline short f2bf(float f) {  // RNE float->bf16
    unsigned u = __builtin_bit_cast(unsigned, f);
    u += 0x7fffu + ((u >> 16) & 1u);
    return (short)(u >> 16);
}

// ---------------- GEMM: h = feats @ weight via bf16 MFMA ----------------
// Block = 256 threads (4 waves) = 64 nodes; wave = 16 nodes x 64 cols.
// A-frag: row=lane&15, k=(lane>>4)*8+i (from global, converted on the fly).
// B-frag: col=lane&15, same k (from transposed padded LDS tile).
// C: col=lane&15, row=(lane>>4)*4+reg  [m89-verified layout].
__global__ __launch_bounds__(256) void gemm_kernel(
        const float* __restrict__ feats, const float* __restrict__ weight,
        float* __restrict__ h, int n_nodes) {
    __shared__ short wbT[OUT_F][IN_F + 8];  // bf16, transposed, pad 8 halfs (row stride 272 B)

    for (int idx = threadIdx.x; idx < IN_F * OUT_F; idx += 256)
        wbT[idx & 63][idx >> 6] = f2bf(weight[idx]);   // coalesced read, LDS transpose write
    __syncthreads();

    const int lane  = threadIdx.x & 63;
    const int wid   = threadIdx.x >> 6;
    const int arow  = lane & 15;   // A row within 16-node tile
    const int kg    = lane >> 4;   // k-group 0..3
    const int node0 = blockIdx.x * 64 + wid * 16;

    const int an = min(node0 + arow, n_nodes - 1);  // clamp (invalid rows not stored)
    const float* ap = feats + (size_t)an * IN_F;

    f32x4 acc[4] = {{0,0,0,0},{0,0,0,0},{0,0,0,0},{0,0,0,0}};

    #pragma unroll
    for (int ks = 0; ks < 4; ++ks) {                 // K-step of 32
        const int kbase = ks * 32 + kg * 8;
        const float4 a0 = *reinterpret_cast<const float4*>(ap + kbase);
        const float4 a1 = *reinterpret_cast<const float4*>(ap + kbase + 4);
        bf16x8 a;
        a[0] = f2bf(a0.x); a[1] = f2bf(a0.y); a[2] = f2bf(a0.z); a[3] = f2bf(a0.w);
        a[4] = f2bf(a1.x); a[5] = f2bf(a1.y); a[6] = f2bf(a1.z); a[7] = f2bf(a1.w);
        #pragma unroll
        for (int nt = 0; nt < 4; ++nt) {
            const bf16x8 b = *reinterpret_cast<const bf16x8*>(&wbT[nt * 16 + (lane & 15)][kbase]);
            acc[nt] = __builtin_amdgcn_mfma_f32_16x16x32_bf16(a, b, acc[nt], 0, 0, 0);
        }
    }

    #pragma unroll
    for (int nt = 0; nt < 4; ++nt) {
        #pragma unroll
        for (int r = 0; r < 4; ++r) {
            const int n = node0 + (lane >> 4) * 4 + r;   // C row
            if (n < n_nodes)
                h[(size_t)n * OUT_F + nt * 16 + (lane & 15)] = acc[nt][r];
        }
    }
}

// ---------------- B1: per-chunk LDS histogram over bins ----------------
__global__ void hist_kernel(const int* __restrict__ dst, int* __restrict__ histmat,
                            int E, int nbins) {
    __shared__ int hl[MAX_BINS];
    const int k = blockIdx.x;
    const int chunk = (E + NB_BLOCKS - 1) / NB_BLOCKS;
    const int beg = k * chunk, end = min(E, beg + chunk);
    for (int i = threadIdx.x; i < nbins; i += blockDim.x) hl[i] = 0;
    __syncthreads();
    for (int e = beg + threadIdx.x; e < end; e += blockDim.x)
        atomicAdd(&hl[dst[e] >> BIN_SHIFT], 1);
    __syncthreads();
    for (int i = threadIdx.x; i < nbins; i += blockDim.x)
        histmat[k * nbins + i] = hl[i];
}

// ---------------- S1: per-bin exclusive scan over the 256 chunks ----------------
__global__ void colscan_kernel(int* __restrict__ histmat, int* __restrict__ tot, int nbins) {
    __shared__ int s[NB_BLOCKS];
    const int b = blockIdx.x;
    const int t = threadIdx.x;
    const int v = histmat[t * nbins + b];
    s[t] = v;
    __syncthreads();
    for (int off = 1; off < NB_BLOCKS; off <<= 1) {
        const int u = (t >= off) ? s[t - off] : 0;
        __syncthreads();
        s[t] += u;
        __syncthreads();
    }
    histmat[t * nbins + b] = s[t] - v;  // exclusive over blocks
    if (t == NB_BLOCKS - 1) tot[b] = s[t];
}

// ---------------- S2: exclusive scan of bin totals ----------------
__global__ void binscan_kernel(const int* __restrict__ tot, int* __restrict__ binbase,
                               int nbins, int E) {
    __shared__ int s[MAX_BINS];
    const int t = threadIdx.x;
    const int v = (t < nbins) ? tot[t] : 0;
    s[t] = v;
    __syncthreads();
    for (int off = 1; off < MAX_BINS; off <<= 1) {
        const int u = (t >= off) ? s[t - off] : 0;
        __syncthreads();
        s[t] += u;
        __syncthreads();
    }
    if (t < nbins) binbase[t] = s[t] - v;
    if (t == 0) binbase[nbins] = E;
}

// ---------------- B2: deterministic scatter into bins (LDS cursors only) ----------------
__global__ void scatter_kernel(const int* __restrict__ src, const int* __restrict__ dst,
                               const int* __restrict__ colscan, const int* __restrict__ binbase,
                               unsigned int* __restrict__ bucket, int E, int nbins) {
    __shared__ int cur[MAX_BINS];
    const int k = blockIdx.x;
    for (int i = threadIdx.x; i < nbins; i += blockDim.x)
        cur[i] = binbase[i] + colscan[k * nbins + i];
    __syncthreads();
    const int chunk = (E + NB_BLOCKS - 1) / NB_BLOCKS;
    const int beg = k * chunk, end = min(E, beg + chunk);
    for (int e = beg + threadIdx.x; e < end; e += blockDim.x) {
        const int d = dst[e];
        const int pos = atomicAdd(&cur[d >> BIN_SHIFT], 1);
        bucket[pos] = ((unsigned)(d & 63) << 16) | (unsigned)src[e];  // src < 65536
    }
}

// ---------------- B3: per-bin counting sort (in place) -> per-node CSR offs ----------------
__global__ void binsort_kernel(unsigned int* __restrict__ bucket,
                               const int* __restrict__ binbase,
                               int* __restrict__ offs, int N, int E, int nbins) {
    __shared__ unsigned buf[BIN_CAP];  // 32 KB
    __shared__ int cnt64[64];
    __shared__ int off64[64];
    const int b    = blockIdx.x;
    const int base = binbase[b], end = binbase[b + 1];
    const int cnt  = end - base;

    for (int i = threadIdx.x; i < cnt; i += 256) buf[i] = bucket[base + i];
    if (threadIdx.x < 64) cnt64[threadIdx.x] = 0;
    __syncthreads();
    for (int i = threadIdx.x; i < cnt; i += 256)
        atomicAdd(&cnt64[buf[i] >> 16], 1);
    __syncthreads();

    int v = 0;
    if (threadIdx.x < 64) { v = cnt64[threadIdx.x]; off64[threadIdx.x] = v; }
    __syncthreads();
    for (int off = 1; off < 64; off <<= 1) {
        int u = 0;
        if (threadIdx.x >= off && threadIdx.x < 64) u = off64[threadIdx.x - off];
        __syncthreads();
        if (threadIdx.x < 64) off64[threadIdx.x] += u;
        __syncthreads();
    }
    if (threadIdx.x < 64) {
        const int excl = off64[threadIdx.x] - v;
        const int node = (b << BIN_SHIFT) + threadIdx.x;
        if (node < N) offs[node] = base + excl;
        off64[threadIdx.x] = excl;  // becomes the scatter cursor
    }
    __syncthreads();

    for (int i = threadIdx.x; i < cnt; i += 256) {
        const unsigned wdv = buf[i];
        const int pos = atomicAdd(&off64[wdv >> 16], 1);
        bucket[base + pos] = wdv;
    }
    if (b == nbins - 1 && threadIdx.x == 0) offs[N] = E;
}

// ---------------- C: pull-mode CSR gather + bias + ReLU ----------------
__global__ __launch_bounds__(256) void gather_kernel(
        const float* __restrict__ h, const unsigned int* __restrict__ bucket,
        const int* __restrict__ offs, const float* __restrict__ bias,
        float* __restrict__ out, int N) {
    const int lane   = threadIdx.x & 63;
    const int gwave  = (blockIdx.x * blockDim.x + threadIdx.x) >> 6;
    const int nwaves = (gridDim.x * blockDim.x) >> 6;
    const float b = bias[lane];
    for (int n = gwave; n < N; n += nwaves) {
        const int beg = offs[n], end = offs[n + 1];
        float acc = 0.f;
        int i = beg;
        for (; i + 8 <= end; i += 8) {
            const unsigned w0 = bucket[i + 0], w1 = bucket[i + 1];
            const unsigned w2 = bucket[i + 2], w3 = bucket[i + 3];
            const unsigned w4 = bucket[i + 4], w5 = bucket[i + 5];
            const unsigned w6 = bucket[i + 6], w7 = bucket[i + 7];
            const float v0 = h[(size_t)(w0 & 0xffffu) * OUT_F + lane];
            const float v1 = h[(size_t)(w1 & 0xffffu) * OUT_F + lane];
            const float v2 = h[(size_t)(w2 & 0xffffu) * OUT_F + lane];
            const float v3 = h[(size_t)(w3 & 0xffffu) * OUT_F + lane];
            const float v4 = h[(size_t)(w4 & 0xffffu) * OUT_F + lane];
            const float v5 = h[(size_t)(w5 & 0xffffu) * OUT_F + lane];
            const float v6 = h[(size_t)(w6 & 0xffffu) * OUT_F + lane];
            const float v7 = h[(size_t)(w7 & 0xffffu) * OUT_F + lane];
            acc += v0; acc += v1; acc += v2; acc += v3;
            acc += v4; acc += v5; acc += v6; acc += v7;
        }
        for (; i < end; ++i)
            acc += h[(size_t)(bucket[i] & 0xffffu) * OUT_F + lane];
        out[(size_t)n * OUT_F + lane] = fmaxf(acc + b, 0.f);
    }
}

extern "C" void kernel_launch(void* const* d_in, const int* in_sizes, int n_in,
                              void* d_out, int out_size, void* d_ws, size_t ws_size,
                              hipStream_t stream) {
    const float* feats  = (const float*)d_in[0];
    const float* weight = (const float*)d_in[1];
    const float* bias   = (const float*)d_in[2];
    const int*   src    = (const int*)d_in[3];
    const int*   dst    = (const int*)d_in[4];
    float* out = (float*)d_out;

    const int N = in_sizes[0] / IN_F;
    const int E = in_sizes[3];
    const int nbins = (N + 63) >> BIN_SHIFT;  // 782 for N=50000

    // workspace layout (~17.2 MB)
    float*    h       = (float*)d_ws;                       // N*64 f32
    unsigned* bucket  = (unsigned*)(h + (size_t)N * OUT_F); // E words
    int*      histmat = (int*)(bucket + E);                 // NB_BLOCKS * nbins
    int*      tot     = histmat + NB_BLOCKS * nbins;        // nbins
    int*      binbase = tot + nbins;                        // nbins + 1
    int*      offs    = binbase + nbins + 1;                // N + 1

    gemm_kernel<<<(N + 63) / 64, 256, 0, stream>>>(feats, weight, h, N);
    hist_kernel<<<NB_BLOCKS, 256, 0, stream>>>(dst, histmat, E, nbins);
    colscan_kernel<<<nbins, NB_BLOCKS, 0, stream>>>(histmat, tot, nbins);
    binscan_kernel<<<1, MAX_BINS, 0, stream>>>(tot, binbase, nbins, E);
    scatter_kernel<<<NB_BLOCKS, 256, 0, stream>>>(src, dst, histmat, binbase, bucket, E, nbins);
    binsort_kernel<<<nbins, 256, 0, stream>>>(bucket, binbase, offs, N, E, nbins);
    // 2048 x 256 = 8192 waves = full residency; writes every out row (no memset needed)
    gather_kernel<<<2048, 256, 0, stream>>>(h, bucket, offs, bias, out, N);
}

// Round 14
// 148.283 us; speedup vs baseline: 3.2408x; 1.0265x over previous
//
#include <hip/hip_runtime.h>

constexpr int IN_F  = 128;
constexpr int OUT_F = 64;
constexpr int NB_BLOCKS = 256;   // edge-chunk blocks; == colscan block size
constexpr int BIN_SHIFT = 6;     // 64 nodes per bin
constexpr int MAX_BINS  = 1024;  // N <= 65536
constexpr int BIN_CAP   = 8192;  // binsort LDS capacity (words)

using bf16x8 = __attribute__((ext_vector_type(8))) short;  // 8 bf16 in 4 VGPRs
using f32x4  = __attribute__((ext_vector_type(4))) float;

__device__ inline short f2bf(float f) {  // RNE float->bf16
    unsigned u = __builtin_bit_cast(unsigned, f);
    u += 0x7fffu + ((u >> 16) & 1u);
    return (short)(u >> 16);
}
__device__ inline float bf2f(unsigned short u) {
    unsigned x = ((unsigned)u) << 16;
    return __builtin_bit_cast(float, x);
}

// ---------------- GEMM: h(bf16) = feats @ weight via bf16 MFMA ----------------
// Block = 256 threads (4 waves) = 64 nodes; wave = 16 nodes x 64 cols.
// A-frag: row=lane&15, k=(lane>>4)*8+i. B-frag: col=lane&15, same k (transposed LDS).
// C: col=lane&15, row=(lane>>4)*4+reg  [m89-verified layout].
__global__ __launch_bounds__(256) void gemm_kernel(
        const float* __restrict__ feats, const float* __restrict__ weight,
        unsigned short* __restrict__ h, int n_nodes) {
    __shared__ short wbT[OUT_F][IN_F + 8];  // bf16, transposed, pad 8 halfs

    for (int idx = threadIdx.x; idx < IN_F * OUT_F; idx += 256)
        wbT[idx & 63][idx >> 6] = f2bf(weight[idx]);   // coalesced read, LDS transpose write
    __syncthreads();

    const int lane  = threadIdx.x & 63;
    const int wid   = threadIdx.x >> 6;
    const int arow  = lane & 15;
    const int kg    = lane >> 4;
    const int node0 = blockIdx.x * 64 + wid * 16;

    const int an = min(node0 + arow, n_nodes - 1);  // clamp (invalid rows not stored)
    const float* ap = feats + (size_t)an * IN_F;

    f32x4 acc[4] = {{0,0,0,0},{0,0,0,0},{0,0,0,0},{0,0,0,0}};

    #pragma unroll
    for (int ks = 0; ks < 4; ++ks) {                 // K-step of 32
        const int kbase = ks * 32 + kg * 8;
        const float4 a0 = *reinterpret_cast<const float4*>(ap + kbase);
        const float4 a1 = *reinterpret_cast<const float4*>(ap + kbase + 4);
        bf16x8 a;
        a[0] = f2bf(a0.x); a[1] = f2bf(a0.y); a[2] = f2bf(a0.z); a[3] = f2bf(a0.w);
        a[4] = f2bf(a1.x); a[5] = f2bf(a1.y); a[6] = f2bf(a1.z); a[7] = f2bf(a1.w);
        #pragma unroll
        for (int nt = 0; nt < 4; ++nt) {
            const bf16x8 b = *reinterpret_cast<const bf16x8*>(&wbT[nt * 16 + (lane & 15)][kbase]);
            acc[nt] = __builtin_amdgcn_mfma_f32_16x16x32_bf16(a, b, acc[nt], 0, 0, 0);
        }
    }

    #pragma unroll
    for (int nt = 0; nt < 4; ++nt) {
        #pragma unroll
        for (int r = 0; r < 4; ++r) {
            const int n = node0 + (lane >> 4) * 4 + r;   // C row
            if (n < n_nodes)
                h[(size_t)n * OUT_F + nt * 16 + (lane & 15)] = (unsigned short)f2bf(acc[nt][r]);
        }
    }
}

// ---------------- B1: per-chunk LDS histogram over bins ----------------
__global__ void hist_kernel(const int* __restrict__ dst, int* __restrict__ histmat,
                            int E, int nbins) {
    __shared__ int hl[MAX_BINS];
    const int k = blockIdx.x;
    const int chunk = (E + NB_BLOCKS - 1) / NB_BLOCKS;
    const int beg = k * chunk, end = min(E, beg + chunk);
    for (int i = threadIdx.x; i < nbins; i += blockDim.x) hl[i] = 0;
    __syncthreads();
    for (int e = beg + threadIdx.x; e < end; e += blockDim.x)
        atomicAdd(&hl[dst[e] >> BIN_SHIFT], 1);
    __syncthreads();
    for (int i = threadIdx.x; i < nbins; i += blockDim.x)
        histmat[k * nbins + i] = hl[i];
}

// ---------------- S1: per-bin exclusive scan over the 256 chunks ----------------
__global__ void colscan_kernel(int* __restrict__ histmat, int* __restrict__ tot, int nbins) {
    __shared__ int s[NB_BLOCKS];
    const int b = blockIdx.x;
    const int t = threadIdx.x;
    const int v = histmat[t * nbins + b];
    s[t] = v;
    __syncthreads();
    for (int off = 1; off < NB_BLOCKS; off <<= 1) {
        const int u = (t >= off) ? s[t - off] : 0;
        __syncthreads();
        s[t] += u;
        __syncthreads();
    }
    histmat[t * nbins + b] = s[t] - v;  // exclusive over blocks
    if (t == NB_BLOCKS - 1) tot[b] = s[t];
}

// ---------------- S2: exclusive scan of bin totals ----------------
__global__ void binscan_kernel(const int* __restrict__ tot, int* __restrict__ binbase,
                               int nbins, int E) {
    __shared__ int s[MAX_BINS];
    const int t = threadIdx.x;
    const int v = (t < nbins) ? tot[t] : 0;
    s[t] = v;
    __syncthreads();
    for (int off = 1; off < MAX_BINS; off <<= 1) {
        const int u = (t >= off) ? s[t - off] : 0;
        __syncthreads();
        s[t] += u;
        __syncthreads();
    }
    if (t < nbins) binbase[t] = s[t] - v;
    if (t == 0) binbase[nbins] = E;
}

// ---------------- B2: deterministic scatter into bins (LDS cursors only) ----------------
__global__ void scatter_kernel(const int* __restrict__ src, const int* __restrict__ dst,
                               const int* __restrict__ colscan, const int* __restrict__ binbase,
                               unsigned int* __restrict__ bucket, int E, int nbins) {
    __shared__ int cur[MAX_BINS];
    const int k = blockIdx.x;
    for (int i = threadIdx.x; i < nbins; i += blockDim.x)
        cur[i] = binbase[i] + colscan[k * nbins + i];
    __syncthreads();
    const int chunk = (E + NB_BLOCKS - 1) / NB_BLOCKS;
    const int beg = k * chunk, end = min(E, beg + chunk);
    for (int e = beg + threadIdx.x; e < end; e += blockDim.x) {
        const int d = dst[e];
        const int pos = atomicAdd(&cur[d >> BIN_SHIFT], 1);
        bucket[pos] = ((unsigned)(d & 63) << 16) | (unsigned)src[e];  // src < 65536
    }
}

// ---------------- B3: per-bin counting sort (in place) -> per-node CSR offs ----------------
__global__ void binsort_kernel(unsigned int* __restrict__ bucket,
                               const int* __restrict__ binbase,
                               int* __restrict__ offs, int N, int E, int nbins) {
    __shared__ unsigned buf[BIN_CAP];  // 32 KB
    __shared__ int cnt64[64];
    __shared__ int off64[64];
    const int b    = blockIdx.x;
    const int base = binbase[b], end = binbase[b + 1];
    const int cnt  = end - base;

    for (int i = threadIdx.x; i < cnt; i += 256) buf[i] = bucket[base + i];
    if (threadIdx.x < 64) cnt64[threadIdx.x] = 0;
    __syncthreads();
    for (int i = threadIdx.x; i < cnt; i += 256)
        atomicAdd(&cnt64[buf[i] >> 16], 1);
    __syncthreads();

    int v = 0;
    if (threadIdx.x < 64) { v = cnt64[threadIdx.x]; off64[threadIdx.x] = v; }
    __syncthreads();
    for (int off = 1; off < 64; off <<= 1) {
        int u = 0;
        if (threadIdx.x >= off && threadIdx.x < 64) u = off64[threadIdx.x - off];
        __syncthreads();
        if (threadIdx.x < 64) off64[threadIdx.x] += u;
        __syncthreads();
    }
    if (threadIdx.x < 64) {
        const int excl = off64[threadIdx.x] - v;
        const int node = (b << BIN_SHIFT) + threadIdx.x;
        if (node < N) offs[node] = base + excl;
        off64[threadIdx.x] = excl;  // becomes the scatter cursor
    }
    __syncthreads();

    for (int i = threadIdx.x; i < cnt; i += 256) {
        const unsigned wdv = buf[i];
        const int pos = atomicAdd(&off64[wdv >> 16], 1);
        bucket[base + pos] = wdv;
    }
    if (b == nbins - 1 && threadIdx.x == 0) offs[N] = E;
}

// ---------------- C: pull-mode CSR gather (bf16 h) + bias + ReLU ----------------
__global__ __launch_bounds__(256) void gather_kernel(
        const unsigned short* __restrict__ h, const unsigned int* __restrict__ bucket,
        const int* __restrict__ offs, const float* __restrict__ bias,
        float* __restrict__ out, int N) {
    const int lane   = threadIdx.x & 63;
    const int gwave  = (blockIdx.x * blockDim.x + threadIdx.x) >> 6;
    const int nwaves = (gridDim.x * blockDim.x) >> 6;
    const float b = bias[lane];
    for (int n = gwave; n < N; n += nwaves) {
        const int beg = offs[n], end = offs[n + 1];
        float acc = 0.f;
        int i = beg;
        for (; i + 8 <= end; i += 8) {
            const unsigned w0 = bucket[i + 0], w1 = bucket[i + 1];
            const unsigned w2 = bucket[i + 2], w3 = bucket[i + 3];
            const unsigned w4 = bucket[i + 4], w5 = bucket[i + 5];
            const unsigned w6 = bucket[i + 6], w7 = bucket[i + 7];
            const unsigned short u0 = h[(size_t)(w0 & 0xffffu) * OUT_F + lane];
            const unsigned short u1 = h[(size_t)(w1 & 0xffffu) * OUT_F + lane];
            const unsigned short u2 = h[(size_t)(w2 & 0xffffu) * OUT_F + lane];
            const unsigned short u3 = h[(size_t)(w3 & 0xffffu) * OUT_F + lane];
            const unsigned short u4 = h[(size_t)(w4 & 0xffffu) * OUT_F + lane];
            const unsigned short u5 = h[(size_t)(w5 & 0xffffu) * OUT_F + lane];
            const unsigned short u6 = h[(size_t)(w6 & 0xffffu) * OUT_F + lane];
            const unsigned short u7 = h[(size_t)(w7 & 0xffffu) * OUT_F + lane];
            acc += bf2f(u0); acc += bf2f(u1); acc += bf2f(u2); acc += bf2f(u3);
            acc += bf2f(u4); acc += bf2f(u5); acc += bf2f(u6); acc += bf2f(u7);
        }
        for (; i < end; ++i)
            acc += bf2f(h[(size_t)(bucket[i] & 0xffffu) * OUT_F + lane]);
        out[(size_t)n * OUT_F + lane] = fmaxf(acc + b, 0.f);
    }
}

extern "C" void kernel_launch(void* const* d_in, const int* in_sizes, int n_in,
                              void* d_out, int out_size, void* d_ws, size_t ws_size,
                              hipStream_t stream) {
    const float* feats  = (const float*)d_in[0];
    const float* weight = (const float*)d_in[1];
    const float* bias   = (const float*)d_in[2];
    const int*   src    = (const int*)d_in[3];
    const int*   dst    = (const int*)d_in[4];
    float* out = (float*)d_out;

    const int N = in_sizes[0] / IN_F;
    const int E = in_sizes[3];
    const int nbins = (N + 63) >> BIN_SHIFT;  // 782 for N=50000

    // workspace layout (~11 MB)
    unsigned short* h = (unsigned short*)d_ws;              // N*64 bf16
    unsigned* bucket  = (unsigned*)(h + (size_t)N * OUT_F); // E words
    int*      histmat = (int*)(bucket + E);                 // NB_BLOCKS * nbins
    int*      tot     = histmat + NB_BLOCKS * nbins;        // nbins
    int*      binbase = tot + nbins;                        // nbins + 1
    int*      offs    = binbase + nbins + 1;                // N + 1

    gemm_kernel<<<(N + 63) / 64, 256, 0, stream>>>(feats, weight, h, N);
    hist_kernel<<<NB_BLOCKS, 256, 0, stream>>>(dst, histmat, E, nbins);
    colscan_kernel<<<nbins, NB_BLOCKS, 0, stream>>>(histmat, tot, nbins);
    binscan_kernel<<<1, MAX_BINS, 0, stream>>>(tot, binbase, nbins, E);
    scatter_kernel<<<NB_BLOCKS, 256, 0, stream>>>(src, dst, histmat, binbase, bucket, E, nbins);
    binsort_kernel<<<nbins, 256, 0, stream>>>(bucket, binbase, offs, N, E, nbins);
    // 2048 x 256 = 8192 waves = full residency; writes every out row (no memset needed)
    gather_kernel<<<2048, 256, 0, stream>>>(h, bucket, offs, bias, out, N);
}